// Round 6
// baseline (2335.467 us; speedup 1.0000x reference)
//
#include <hip/hip_runtime.h>

#define N_NODES 50000
#define N_EDGES 800000
#define CH 128
#define N_GRAPHS 128
#define N_LAYERS 3
#define OUT_CH 16
#define BN_EPS 1e-5f
#define NSPLIT 8
#define NB 196          // dst>>8 tiles (256 dsts each)
#define BCAP 4608       // bucket capacity (mean 4082, +8 sigma)
#define EPB 4096        // edges per bin block

typedef unsigned short ushort_t;
typedef __attribute__((ext_vector_type(8))) short bf16x8;
typedef __attribute__((ext_vector_type(4))) float f32x4;

__device__ inline ushort_t f2b(float f) {
    unsigned u = __float_as_uint(f);
    unsigned r = (u + 0x7fffu + ((u >> 16) & 1u)) >> 16;
    return (ushort_t)r;
}
__device__ inline float b2f(ushort_t b) { return __uint_as_float((unsigned)b << 16); }
__device__ inline float blo(unsigned u) { return __uint_as_float(u << 16); }
__device__ inline float bhi(unsigned u) { return __uint_as_float(u & 0xffff0000u); }

// ---------------- fp32 x -> bf16 flat [N][128] ----------------
__global__ __launch_bounds__(256) void cast_kernel(const float4* __restrict__ x,
                                                   ushort4* __restrict__ xb, int n4) {
    int i = blockIdx.x * blockDim.x + threadIdx.x;
    if (i >= n4) return;
    float4 v = x[i];
    ushort4 o;
    o.x = f2b(v.x); o.y = f2b(v.y); o.z = f2b(v.z); o.w = f2b(v.w);
    xb[i] = o;
}

// ---------------- edge binning: pack = src | (dst&255)<<16, bucket = dst>>8 ----------------
__global__ __launch_bounds__(256) void bin_kernel(const int* __restrict__ src,
                                                  const int* __restrict__ dst,
                                                  int* __restrict__ gcur,
                                                  unsigned* __restrict__ gbuck) {
    __shared__ int lcnt[256];
    __shared__ int lpref[256];
    __shared__ int lpos[NB];
    __shared__ int lbase[NB];
    __shared__ unsigned stage[EPB];
    __shared__ unsigned char sbk[EPB];
    int t = threadIdx.x;
    int e0 = blockIdx.x * EPB;
    int nloc = N_EDGES - e0; if (nloc > EPB) nloc = EPB;

    lcnt[t] = 0;
    __syncthreads();

    int2 ed[16];
    #pragma unroll
    for (int j = 0; j < 16; ++j) {
        int i = j * 256 + t;
        if (i < nloc) {
            ed[j].x = src[e0 + i];
            ed[j].y = dst[e0 + i];
            atomicAdd(&lcnt[ed[j].y >> 8], 1);
        } else ed[j].y = -1;
    }
    __syncthreads();
    int v = lcnt[t];
    lpref[t] = v;
    __syncthreads();
    for (int off = 1; off < 256; off <<= 1) {
        int y = (t >= off) ? lpref[t - off] : 0;
        __syncthreads();
        lpref[t] += y;
        __syncthreads();
    }
    int excl = lpref[t] - v;
    __syncthreads();
    lpref[t] = excl;
    if (t < NB) {
        lpos[t] = excl;
        lbase[t] = atomicAdd(&gcur[t], v);
    }
    __syncthreads();
    #pragma unroll
    for (int j = 0; j < 16; ++j) {
        if (ed[j].y >= 0) {
            int b = ed[j].y >> 8;
            int slot = atomicAdd(&lpos[b], 1);
            stage[slot] = (unsigned)ed[j].x | ((unsigned)(ed[j].y & 255) << 16);
            sbk[slot] = (unsigned char)b;
        }
    }
    __syncthreads();
    for (int i = t; i < nloc; i += 256) {
        int b = sbk[i];
        gbuck[(size_t)b * BCAP + lbase[b] + (i - lpref[b])] = stage[i];
    }
}

// ---------------- per-tile 8-way counting sort by src>>13 ----------------
__global__ __launch_bounds__(256) void qsort_kernel(const int* __restrict__ gcur,
                                                    unsigned* __restrict__ gbuck,
                                                    int* __restrict__ qoff) {
    __shared__ unsigned sin_[BCAP];
    __shared__ unsigned sout_[BCAP];
    __shared__ int cnt[8], off[9], cur[8];
    int b = blockIdx.x, t = threadIdx.x;
    int n = gcur[b];
    if (t < 8) { cnt[t] = 0; cur[t] = 0; }
    __syncthreads();
    for (int i = t; i < n; i += 256) {
        unsigned p = gbuck[(size_t)b * BCAP + i];
        sin_[i] = p;
        atomicAdd(&cnt[(p & 0xffffu) >> 13], 1);
    }
    __syncthreads();
    if (t == 0) {
        off[0] = 0;
        for (int k = 0; k < 8; ++k) off[k + 1] = off[k] + cnt[k];
    }
    __syncthreads();
    for (int i = t; i < n; i += 256) {
        unsigned p = sin_[i];
        int g = (p & 0xffffu) >> 13;
        int pos = off[g] + atomicAdd(&cur[g], 1);
        sout_[pos] = p;
    }
    __syncthreads();
    for (int i = t; i < n; i += 256) gbuck[(size_t)b * BCAP + i] = sout_[i];
    if (t < 9) qoff[b * 9 + t] = off[t];
}

__global__ void starts_kernel(const int* __restrict__ batch, int* __restrict__ starts) {
    int i = blockIdx.x * blockDim.x + threadIdx.x;
    if (i >= N_NODES) return;
    int b = batch[i];
    if (i == 0) {
        for (int g = 0; g <= b; ++g) starts[g] = 0;
    } else {
        int pb = batch[i - 1];
        for (int g = pb + 1; g <= b; ++g) starts[g] = i;
    }
    if (i == N_NODES - 1) {
        for (int g = b + 1; g <= N_GRAPHS; ++g) starts[g] = N_NODES;
    }
}

// ---------------- weight / epilogue prep ----------------
__global__ __launch_bounds__(256) void wprep_kernel(const float* __restrict__ W1,
                                                    const float* __restrict__ W2,
                                                    ushort_t* __restrict__ Wt) {
    int i = blockIdx.x * blockDim.x + threadIdx.x;
    if (i >= 6 * CH * CH) return;
    int mat = i / (CH * CH), rem = i % (CH * CH);
    int n = rem / CH, k = rem % CH;
    const float* Wsrc = (mat < 3) ? (W1 + (size_t)mat * CH * CH)
                                  : (W2 + (size_t)(mat - 3) * CH * CH);
    Wt[i] = f2b(Wsrc[k * CH + n]);
}

__global__ void eprep_kernel(const float* __restrict__ b1, const float* __restrict__ b2,
                             const float* __restrict__ gamma, const float* __restrict__ beta,
                             const float* __restrict__ mean, const float* __restrict__ var,
                             float* __restrict__ scale, float* __restrict__ shift) {
    int i = blockIdx.x * blockDim.x + threadIdx.x;
    if (i >= 6 * CH) return;
    int mat = i / CH, c = i % CH;
    if (mat < 3) {
        scale[i] = 1.f;
        shift[i] = b1[mat * CH + c];
    } else {
        int l = mat - 3;
        float inv = gamma[l * CH + c] * rsqrtf(var[l * CH + c] + BN_EPS);
        scale[i] = inv;
        shift[i] = (b2[l * CH + c] - mean[l * CH + c]) * inv + beta[l * CH + c];
    }
}

// ---------------- push aggregation: block = 256-dst tile, LDS fp32 accumulator ----------------
// Edges sorted by src>>13: all co-resident blocks sweep the same 2MB src slice (L2-resident).
// acc layout: [dl][c'] with c'=lane -> ch 2*lane (even), c'=64+lane -> ch 2*lane+1 (odd).
__global__ __launch_bounds__(512) void agg_kernel(const unsigned* __restrict__ h2,
                                                  const unsigned* __restrict__ gbuck,
                                                  const int* __restrict__ qoff,
                                                  unsigned* __restrict__ z2) {
    __shared__ float acc[256 * 128];   // 128 KB
    int t = threadIdx.x;
    int wave = t >> 6, lane = t & 63;
    int tile = blockIdx.x;

    {   // zero LDS
        uint4* a4 = (uint4*)acc;
        uint4 z = {0u, 0u, 0u, 0u};
        for (int i = t; i < 256 * 128 / 4; i += 512) a4[i] = z;
    }
    __syncthreads();

    const unsigned* bucket = gbuck + (size_t)tile * BCAP;
    const int* qo = qoff + tile * 9;

    for (int g = 0; g < 8; ++g) {
        int s = qo[g], len = qo[g + 1] - s;
        int w0 = s + (len * wave) / 8;
        int w1 = s + (len * (wave + 1)) / 8;
        for (int e = w0; e < w1; e += 64) {
            int m = w1 - e; if (m > 64) m = 64;
            unsigned p = (lane < m) ? bucket[e + lane] : 0u;
            int j = 0;
            for (; j + 4 <= m; j += 4) {
                unsigned p0 = (unsigned)__shfl((int)p, j);
                unsigned p1 = (unsigned)__shfl((int)p, j + 1);
                unsigned p2 = (unsigned)__shfl((int)p, j + 2);
                unsigned p3 = (unsigned)__shfl((int)p, j + 3);
                unsigned u0 = h2[(size_t)(p0 & 0xffffu) * 64 + lane];
                unsigned u1 = h2[(size_t)(p1 & 0xffffu) * 64 + lane];
                unsigned u2 = h2[(size_t)(p2 & 0xffffu) * 64 + lane];
                unsigned u3 = h2[(size_t)(p3 & 0xffffu) * 64 + lane];
                int d0 = (p0 >> 16) & 0xff, d1 = (p1 >> 16) & 0xff;
                int d2 = (p2 >> 16) & 0xff, d3 = (p3 >> 16) & 0xff;
                atomicAdd(&acc[d0 * 128 + lane], blo(u0));
                atomicAdd(&acc[d0 * 128 + 64 + lane], bhi(u0));
                atomicAdd(&acc[d1 * 128 + lane], blo(u1));
                atomicAdd(&acc[d1 * 128 + 64 + lane], bhi(u1));
                atomicAdd(&acc[d2 * 128 + lane], blo(u2));
                atomicAdd(&acc[d2 * 128 + 64 + lane], bhi(u2));
                atomicAdd(&acc[d3 * 128 + lane], blo(u3));
                atomicAdd(&acc[d3 * 128 + 64 + lane], bhi(u3));
            }
            for (; j < m; ++j) {
                unsigned pj = (unsigned)__shfl((int)p, j);
                unsigned u = h2[(size_t)(pj & 0xffffu) * 64 + lane];
                int d = (pj >> 16) & 0xff;
                atomicAdd(&acc[d * 128 + lane], blo(u));
                atomicAdd(&acc[d * 128 + 64 + lane], bhi(u));
            }
        }
    }
    __syncthreads();

    // output: z[node] = acc + h[node]
    int node0 = tile * 256;
    for (int r = wave; r < 256; r += 8) {
        int node = node0 + r;
        if (node >= N_NODES) break;
        unsigned self = h2[(size_t)node * 64 + lane];
        float fx = acc[r * 128 + lane] + blo(self);
        float fy = acc[r * 128 + 64 + lane] + bhi(self);
        z2[(size_t)node * 64 + lane] = ((unsigned)f2b(fy) << 16) | (unsigned)f2b(fx);
    }
}

// ---------------- fused MLP (unchanged from R5) ----------------
__global__ __launch_bounds__(256) void mlp_kernel(const ushort_t* __restrict__ A,
                                                  const ushort_t* __restrict__ Wt1,
                                                  const ushort_t* __restrict__ Wt2,
                                                  const float* __restrict__ shift1,
                                                  const float* __restrict__ scale2,
                                                  const float* __restrict__ shift2,
                                                  ushort_t* __restrict__ Out) {
    __shared__ ushort_t sW[2 * CH * CH];
    __shared__ ushort_t sAx[4][2][16][136];

    int t = threadIdx.x;
    int wave = t >> 6, lane = t & 63;
    int quad = lane >> 4, l16 = lane & 15;

    {
        const uint4* g1 = (const uint4*)Wt1;
        const uint4* g2 = (const uint4*)Wt2;
        uint4* s = (uint4*)sW;
        for (int i = t; i < 2048; i += 256) { s[i] = g1[i]; s[2048 + i] = g2[i]; }
    }
    __syncthreads();

    int rowbase = blockIdx.x * 256 + wave * 64;

    #pragma unroll
    for (int ph = 0; ph < 2; ++ph) {
        int r0 = rowbase + ph * 32;
        bf16x8 af[2][4];
        #pragma unroll
        for (int rt = 0; rt < 2; ++rt) {
            int arow = r0 + rt * 16 + l16;
            if (arow > N_NODES - 1) arow = N_NODES - 1;
            #pragma unroll
            for (int ks = 0; ks < 4; ++ks)
                af[rt][ks] = *(const bf16x8*)(A + (size_t)arow * CH + ks * 32 + quad * 8);
        }
        f32x4 acc[2][8];
        #pragma unroll
        for (int rt = 0; rt < 2; ++rt)
            #pragma unroll
            for (int ct = 0; ct < 8; ++ct) acc[rt][ct] = (f32x4){0.f, 0.f, 0.f, 0.f};
        #pragma unroll
        for (int ct = 0; ct < 8; ++ct)
            #pragma unroll
            for (int ks = 0; ks < 4; ++ks) {
                bf16x8 bf = *(const bf16x8*)&sW[(ct * 16 + l16) * CH + ks * 32 + quad * 8];
                acc[0][ct] = __builtin_amdgcn_mfma_f32_16x16x32_bf16(af[0][ks], bf, acc[0][ct], 0, 0, 0);
                acc[1][ct] = __builtin_amdgcn_mfma_f32_16x16x32_bf16(af[1][ks], bf, acc[1][ct], 0, 0, 0);
            }
        #pragma unroll
        for (int rt = 0; rt < 2; ++rt)
            #pragma unroll
            for (int ct = 0; ct < 8; ++ct) {
                int col = ct * 16 + l16;
                float sh = shift1[col];
                #pragma unroll
                for (int r = 0; r < 4; ++r)
                    sAx[wave][rt][quad * 4 + r][col] = f2b(fmaxf(acc[rt][ct][r] + sh, 0.f));
            }
        bf16x8 af2[2][4];
        #pragma unroll
        for (int rt = 0; rt < 2; ++rt)
            #pragma unroll
            for (int ks = 0; ks < 4; ++ks)
                af2[rt][ks] = *(const bf16x8*)&sAx[wave][rt][l16][ks * 32 + quad * 8];
        f32x4 acc2[2][8];
        #pragma unroll
        for (int rt = 0; rt < 2; ++rt)
            #pragma unroll
            for (int ct = 0; ct < 8; ++ct) acc2[rt][ct] = (f32x4){0.f, 0.f, 0.f, 0.f};
        #pragma unroll
        for (int ct = 0; ct < 8; ++ct)
            #pragma unroll
            for (int ks = 0; ks < 4; ++ks) {
                bf16x8 bf = *(const bf16x8*)&sW[CH * CH + (ct * 16 + l16) * CH + ks * 32 + quad * 8];
                acc2[0][ct] = __builtin_amdgcn_mfma_f32_16x16x32_bf16(af2[0][ks], bf, acc2[0][ct], 0, 0, 0);
                acc2[1][ct] = __builtin_amdgcn_mfma_f32_16x16x32_bf16(af2[1][ks], bf, acc2[1][ct], 0, 0, 0);
            }
        #pragma unroll
        for (int rt = 0; rt < 2; ++rt)
            #pragma unroll
            for (int ct = 0; ct < 8; ++ct) {
                int col = ct * 16 + l16;
                float sc = scale2[col], sh = shift2[col];
                #pragma unroll
                for (int r = 0; r < 4; ++r) {
                    int row = r0 + rt * 16 + quad * 4 + r;
                    if (row < N_NODES)
                        Out[(size_t)row * CH + col] = f2b(fmaxf(acc2[rt][ct][r] * sc + sh, 0.f));
                }
            }
    }
}

// ---------------- pooling + classifier ----------------
__global__ __launch_bounds__(128) void pool_kernel(const ushort_t* __restrict__ h,
                                                   const int* __restrict__ starts,
                                                   float* __restrict__ pooled) {
    int g = blockIdx.x / NSPLIT, s = blockIdx.x % NSPLIT;
    int c = threadIdx.x;
    int beg = starts[g], end = starts[g + 1];
    float sum = 0.f;
    for (int n = beg + s; n < end; n += NSPLIT)
        sum += b2f(h[(size_t)n * CH + c]);
    atomicAdd(&pooled[g * CH + c], sum);
}

__global__ __launch_bounds__(256) void cls_kernel(const float* __restrict__ pooled,
                                                  const float* __restrict__ Wc,
                                                  const float* __restrict__ bc,
                                                  float* __restrict__ out) {
    int i = blockIdx.x * blockDim.x + threadIdx.x;
    if (i >= N_GRAPHS * OUT_CH) return;
    int g = i / OUT_CH, o = i % OUT_CH;
    float s = bc[o];
    for (int k = 0; k < CH; ++k) s += pooled[g * CH + k] * Wc[k * OUT_CH + o];
    out[i] = s;
}

// ---------------- launch ----------------
extern "C" void kernel_launch(void* const* d_in, const int* in_sizes, int n_in,
                              void* d_out, int out_size, void* d_ws, size_t ws_size,
                              hipStream_t stream) {
    const float* x     = (const float*)d_in[0];
    const int*   eidx  = (const int*)d_in[1];
    const int*   batch = (const int*)d_in[2];
    const float* W1    = (const float*)d_in[3];
    const float* b1    = (const float*)d_in[4];
    const float* W2    = (const float*)d_in[5];
    const float* b2    = (const float*)d_in[6];
    const float* gamma = (const float*)d_in[7];
    const float* beta  = (const float*)d_in[8];
    const float* mean  = (const float*)d_in[9];
    const float* var   = (const float*)d_in[10];
    const float* Wc    = (const float*)d_in[11];
    const float* bc    = (const float*)d_in[12];
    float* out = (float*)d_out;

    const int* src = eidx;
    const int* dst = eidx + N_EDGES;

    char* w = (char*)d_ws;
    size_t off = 0;
    auto alloc = [&](size_t bytes) { void* p = w + off; off += (bytes + 255) & ~(size_t)255; return p; };
    int*      gcur   = (int*)alloc(NB * 4);
    unsigned* gbuck  = (unsigned*)alloc((size_t)NB * BCAP * 4);
    int*      qoff   = (int*)alloc(NB * 9 * 4);
    int*      starts = (int*)alloc((N_GRAPHS + 1) * 4);
    ushort_t* Bh     = (ushort_t*)alloc((size_t)N_NODES * CH * 2);
    ushort_t* Bz     = (ushort_t*)alloc((size_t)N_NODES * CH * 2);
    ushort_t* Wt     = (ushort_t*)alloc((size_t)6 * CH * CH * 2);
    float*    scale  = (float*)alloc(6 * CH * 4);
    float*    shift  = (float*)alloc(6 * CH * 4);
    float*    pooled = (float*)alloc(N_GRAPHS * CH * 4);
    (void)ws_size; (void)n_in; (void)in_sizes; (void)out_size;

    const int n4 = (N_NODES * CH) / 4;
    cast_kernel<<<(n4 + 255) / 256, 256, 0, stream>>>((const float4*)x, (ushort4*)Bh, n4);
    hipMemsetAsync(gcur, 0, NB * 4, stream);
    hipMemsetAsync(pooled, 0, N_GRAPHS * CH * 4, stream);
    bin_kernel<<<(N_EDGES + EPB - 1) / EPB, 256, 0, stream>>>(src, dst, gcur, gbuck);
    qsort_kernel<<<NB, 256, 0, stream>>>(gcur, gbuck, qoff);
    starts_kernel<<<(N_NODES + 255) / 256, 256, 0, stream>>>(batch, starts);
    wprep_kernel<<<(6 * CH * CH + 255) / 256, 256, 0, stream>>>(W1, W2, Wt);
    eprep_kernel<<<(6 * CH + 255) / 256, 256, 0, stream>>>(b1, b2, gamma, beta, mean, var, scale, shift);

    const int mlp_grid = (N_NODES + 255) / 256;

    for (int i = 0; i < N_LAYERS; ++i) {
        agg_kernel<<<NB, 512, 0, stream>>>((const unsigned*)Bh, gbuck, qoff, (unsigned*)Bz);
        mlp_kernel<<<mlp_grid, 256, 0, stream>>>(Bz,
                                                 Wt + (size_t)i * CH * CH,
                                                 Wt + (size_t)(3 + i) * CH * CH,
                                                 shift + i * CH,
                                                 scale + (3 + i) * CH,
                                                 shift + (3 + i) * CH,
                                                 Bh);
    }

    pool_kernel<<<N_GRAPHS * NSPLIT, 128, 0, stream>>>(Bh, starts, pooled);
    cls_kernel<<<(N_GRAPHS * OUT_CH + 255) / 256, 256, 0, stream>>>(pooled, Wc, bc, out);
}

// Round 7
// 416.295 us; speedup vs baseline: 5.6101x; 5.6101x over previous
//
#include <hip/hip_runtime.h>

#define N_NODES 50000
#define N_EDGES 800000
#define CH 128
#define N_GRAPHS 128
#define N_LAYERS 3
#define OUT_CH 16
#define BN_EPS 1e-5f
#define NCHUNK ((N_NODES + 1023) / 1024)
#define NSPLIT 8
#define NB 196          // dst>>8 buckets
#define BCAP 4608
#define EPB 4096

typedef unsigned short ushort_t;
typedef __attribute__((ext_vector_type(8))) short bf16x8;
typedef __attribute__((ext_vector_type(4))) float f32x4;

__device__ inline ushort_t f2b(float f) {
    unsigned u = __float_as_uint(f);
    unsigned r = (u + 0x7fffu + ((u >> 16) & 1u)) >> 16;
    return (ushort_t)r;
}
__device__ inline float b2f(ushort_t b) { return __uint_as_float((unsigned)b << 16); }
__device__ inline float blo(unsigned u) { return __uint_as_float(u << 16); }
__device__ inline float bhi(unsigned u) { return __uint_as_float(u & 0xffff0000u); }

// ---------------- fp32 x -> bf16 flat [N][128] ----------------
__global__ __launch_bounds__(256) void cast_kernel(const float4* __restrict__ x,
                                                   ushort4* __restrict__ xb, int n4) {
    int i = blockIdx.x * blockDim.x + threadIdx.x;
    if (i >= n4) return;
    float4 v = x[i];
    ushort4 o;
    o.x = f2b(v.x); o.y = f2b(v.y); o.z = f2b(v.z); o.w = f2b(v.w);
    xb[i] = o;
}

// ---------------- CSR build ----------------
__global__ void hist_kernel(const int* __restrict__ dst, int* __restrict__ deg) {
    int i = blockIdx.x * blockDim.x + threadIdx.x;
    if (i < N_EDGES) atomicAdd(&deg[dst[i]], 1);
}

__global__ __launch_bounds__(1024) void scan1_kernel(const int* __restrict__ deg,
                                                     int* __restrict__ rowptr,
                                                     int* __restrict__ bsum) {
    __shared__ int sdata[1024];
    int t = threadIdx.x, base = blockIdx.x * 1024;
    int v = (base + t < N_NODES) ? deg[base + t] : 0;
    sdata[t] = v;
    __syncthreads();
    #pragma unroll
    for (int off = 1; off < 1024; off <<= 1) {
        int y = (t >= off) ? sdata[t - off] : 0;
        __syncthreads();
        sdata[t] += y;
        __syncthreads();
    }
    if (base + t < N_NODES) rowptr[base + t] = sdata[t] - v;
    if (t == 1023) bsum[blockIdx.x] = sdata[1023];
}

__global__ void scan2_kernel(const int* __restrict__ bsum, int* __restrict__ boff) {
    int lane = threadIdx.x;
    int v = (lane < NCHUNK) ? bsum[lane] : 0;
    int orig = v;
    #pragma unroll
    for (int off = 1; off < 64; off <<= 1) {
        int tv = __shfl_up(v, off);
        if (lane >= off) v += tv;
    }
    if (lane < NCHUNK) boff[lane] = v - orig;
}

__global__ __launch_bounds__(1024) void scan3_kernel(int* __restrict__ rowptr,
                                                     const int* __restrict__ boff) {
    int i = blockIdx.x * 1024 + threadIdx.x;
    if (i < N_NODES) rowptr[i] += boff[blockIdx.x];
    if (i == 0) rowptr[N_NODES] = N_EDGES;
}

// phase 1: bin edges by dst>>8 with LDS staging
__global__ __launch_bounds__(256) void bin_kernel(const int* __restrict__ src,
                                                  const int* __restrict__ dst,
                                                  int* __restrict__ gcur,
                                                  int2* __restrict__ gbuck) {
    __shared__ int lcnt[256];
    __shared__ int lpref[256];
    __shared__ int lpos[NB];
    __shared__ int lbase[NB];
    __shared__ int2 stage[EPB];
    int t = threadIdx.x;
    int e0 = blockIdx.x * EPB;
    int nloc = N_EDGES - e0; if (nloc > EPB) nloc = EPB;

    lcnt[t] = 0;
    __syncthreads();

    int2 ed[16];
    #pragma unroll
    for (int j = 0; j < 16; ++j) {
        int i = j * 256 + t;
        if (i < nloc) {
            ed[j].x = src[e0 + i];
            ed[j].y = dst[e0 + i];
            atomicAdd(&lcnt[ed[j].y >> 8], 1);
        } else ed[j].y = -1;
    }
    __syncthreads();
    int v = lcnt[t];
    lpref[t] = v;
    __syncthreads();
    for (int off = 1; off < 256; off <<= 1) {
        int y = (t >= off) ? lpref[t - off] : 0;
        __syncthreads();
        lpref[t] += y;
        __syncthreads();
    }
    int excl = lpref[t] - v;
    __syncthreads();
    lpref[t] = excl;
    if (t < NB) {
        lpos[t] = excl;
        lbase[t] = atomicAdd(&gcur[t], v);
    }
    __syncthreads();
    #pragma unroll
    for (int j = 0; j < 16; ++j) {
        if (ed[j].y >= 0) {
            int slot = atomicAdd(&lpos[ed[j].y >> 8], 1);
            stage[slot] = ed[j];
        }
    }
    __syncthreads();
    for (int i = t; i < nloc; i += 256) {
        int2 e = stage[i];
        int b = e.y >> 8;
        gbuck[(size_t)b * BCAP + lbase[b] + (i - lpref[b])] = e;
    }
}

// phase 2: per-bucket LDS sort to exact CSR slots, coalesced esrc writes
__global__ __launch_bounds__(256) void place_kernel(const int* __restrict__ gcur,
                                                    const int2* __restrict__ gbuck,
                                                    const int* __restrict__ rowptr,
                                                    int* __restrict__ esrc) {
    __shared__ int ssrc[BCAP];
    __shared__ unsigned char sd[BCAP];
    __shared__ int outS[BCAP];
    __shared__ int cnt[256], pref[256], cur[256];
    int b = blockIdx.x, t = threadIdx.x;
    int nb = gcur[b];
    cnt[t] = 0;
    __syncthreads();
    for (int i = t; i < nb; i += 256) {
        int2 e = gbuck[(size_t)b * BCAP + i];
        ssrc[i] = e.x;
        int dl = e.y & 255;
        sd[i] = (unsigned char)dl;
        atomicAdd(&cnt[dl], 1);
    }
    __syncthreads();
    int v = cnt[t];
    pref[t] = v;
    __syncthreads();
    for (int off = 1; off < 256; off <<= 1) {
        int y = (t >= off) ? pref[t - off] : 0;
        __syncthreads();
        pref[t] += y;
        __syncthreads();
    }
    int excl = pref[t] - v;
    __syncthreads();
    pref[t] = excl;
    cur[t] = 0;
    __syncthreads();
    for (int i = t; i < nb; i += 256) {
        int dl = sd[i];
        int p = pref[dl] + atomicAdd(&cur[dl], 1);
        outS[p] = ssrc[i];
    }
    __syncthreads();
    int base = rowptr[b << 8];
    for (int i = t; i < nb; i += 256)
        esrc[base + i] = outS[i];
}

__global__ void starts_kernel(const int* __restrict__ batch, int* __restrict__ starts) {
    int i = blockIdx.x * blockDim.x + threadIdx.x;
    if (i >= N_NODES) return;
    int b = batch[i];
    if (i == 0) {
        for (int g = 0; g <= b; ++g) starts[g] = 0;
    } else {
        int pb = batch[i - 1];
        for (int g = pb + 1; g <= b; ++g) starts[g] = i;
    }
    if (i == N_NODES - 1) {
        for (int g = b + 1; g <= N_GRAPHS; ++g) starts[g] = N_NODES;
    }
}

// ---------------- weight / epilogue prep ----------------
__global__ __launch_bounds__(256) void wprep_kernel(const float* __restrict__ W1,
                                                    const float* __restrict__ W2,
                                                    ushort_t* __restrict__ Wt) {
    int i = blockIdx.x * blockDim.x + threadIdx.x;
    if (i >= 6 * CH * CH) return;
    int mat = i / (CH * CH), rem = i % (CH * CH);
    int n = rem / CH, k = rem % CH;
    const float* Wsrc = (mat < 3) ? (W1 + (size_t)mat * CH * CH)
                                  : (W2 + (size_t)(mat - 3) * CH * CH);
    Wt[i] = f2b(Wsrc[k * CH + n]);
}

__global__ void eprep_kernel(const float* __restrict__ b1, const float* __restrict__ b2,
                             const float* __restrict__ gamma, const float* __restrict__ beta,
                             const float* __restrict__ mean, const float* __restrict__ var,
                             float* __restrict__ scale, float* __restrict__ shift) {
    int i = blockIdx.x * blockDim.x + threadIdx.x;
    if (i >= 6 * CH) return;
    int mat = i / CH, c = i % CH;
    if (mat < 3) {
        scale[i] = 1.f;
        shift[i] = b1[mat * CH + c];
    } else {
        int l = mat - 3;
        float inv = gamma[l * CH + c] * rsqrtf(var[l * CH + c] + BN_EPS);
        scale[i] = inv;
        shift[i] = (b2[l * CH + c] - mean[l * CH + c]) * inv + beta[l * CH + c];
    }
}

// ---------------- aggregation: pull, wave/node, 16-deep gather unroll ----------------
__global__ __launch_bounds__(256) void agg_kernel(const unsigned* __restrict__ h2,
                                                  const int* __restrict__ rowptr,
                                                  const int* __restrict__ esrc,
                                                  unsigned* __restrict__ z2) {
    int wid = (blockIdx.x * 256 + threadIdx.x) >> 6;
    int lane = threadIdx.x & 63;
    if (wid >= N_NODES) return;
    unsigned self = h2[(size_t)wid * 64 + lane];
    float ax = blo(self), ay = bhi(self);
    int e = rowptr[wid], end = rowptr[wid + 1];
    for (; e + 16 <= end; e += 16) {
        unsigned u[16];
        #pragma unroll
        for (int j = 0; j < 16; ++j) {
            int s = esrc[e + j];
            u[j] = h2[(size_t)s * 64 + lane];
        }
        #pragma unroll
        for (int j = 0; j < 16; ++j) { ax += blo(u[j]); ay += bhi(u[j]); }
    }
    for (; e + 8 <= end; e += 8) {
        unsigned u[8];
        #pragma unroll
        for (int j = 0; j < 8; ++j) {
            int s = esrc[e + j];
            u[j] = h2[(size_t)s * 64 + lane];
        }
        #pragma unroll
        for (int j = 0; j < 8; ++j) { ax += blo(u[j]); ay += bhi(u[j]); }
    }
    for (; e + 4 <= end; e += 4) {
        unsigned u[4];
        #pragma unroll
        for (int j = 0; j < 4; ++j) {
            int s = esrc[e + j];
            u[j] = h2[(size_t)s * 64 + lane];
        }
        #pragma unroll
        for (int j = 0; j < 4; ++j) { ax += blo(u[j]); ay += bhi(u[j]); }
    }
    for (; e < end; ++e) {
        unsigned u = h2[(size_t)esrc[e] * 64 + lane];
        ax += blo(u); ay += bhi(u);
    }
    z2[(size_t)wid * 64 + lane] = ((unsigned)f2b(ay) << 16) | (unsigned)f2b(ax);
}

// ---------------- fused MLP: 384 thr = 6 waves x 32 rows; weights in LDS ----------------
__global__ __launch_bounds__(384) void mlp_kernel(const ushort_t* __restrict__ A,
                                                  const ushort_t* __restrict__ Wt1,
                                                  const ushort_t* __restrict__ Wt2,
                                                  const float* __restrict__ shift1,
                                                  const float* __restrict__ scale2,
                                                  const float* __restrict__ shift2,
                                                  ushort_t* __restrict__ Out) {
    __shared__ ushort_t sW[2 * CH * CH];      // 64 KB
    __shared__ ushort_t sAx[6][16][136];      // 25.5 KB, wave-private strips

    int t = threadIdx.x;
    int wave = t / 64, lane = t & 63;
    int quad = lane >> 4, l16 = lane & 15;

    {
        const uint4* g1 = (const uint4*)Wt1;
        const uint4* g2 = (const uint4*)Wt2;
        uint4* s = (uint4*)sW;
        for (int i = t; i < 2048; i += 384) { s[i] = g1[i]; s[2048 + i] = g2[i]; }
    }
    __syncthreads();

    int rowbase = blockIdx.x * 192 + wave * 32;

    #pragma unroll
    for (int rt = 0; rt < 2; ++rt) {
        int r0 = rowbase + rt * 16;
        if (r0 >= N_NODES) break;
        int arow = r0 + l16;
        if (arow > N_NODES - 1) arow = N_NODES - 1;

        bf16x8 af[4];
        #pragma unroll
        for (int ks = 0; ks < 4; ++ks)
            af[ks] = *(const bf16x8*)(A + (size_t)arow * CH + ks * 32 + quad * 8);

        f32x4 acc[8];
        #pragma unroll
        for (int ct = 0; ct < 8; ++ct) acc[ct] = (f32x4){0.f, 0.f, 0.f, 0.f};
        #pragma unroll
        for (int ct = 0; ct < 8; ++ct)
            #pragma unroll
            for (int ks = 0; ks < 4; ++ks) {
                bf16x8 bf = *(const bf16x8*)&sW[(ct * 16 + l16) * CH + ks * 32 + quad * 8];
                acc[ct] = __builtin_amdgcn_mfma_f32_16x16x32_bf16(af[ks], bf, acc[ct], 0, 0, 0);
            }
        // relu+bias -> wave-private strip (C layout)
        #pragma unroll
        for (int ct = 0; ct < 8; ++ct) {
            int col = ct * 16 + l16;
            float sh = shift1[col];
            #pragma unroll
            for (int r = 0; r < 4; ++r)
                sAx[wave][quad * 4 + r][col] = f2b(fmaxf(acc[ct][r] + sh, 0.f));
        }
        // strip -> A-frag (same-wave lgkm ordering)
        bf16x8 af2[4];
        #pragma unroll
        for (int ks = 0; ks < 4; ++ks)
            af2[ks] = *(const bf16x8*)&sAx[wave][l16][ks * 32 + quad * 8];

        f32x4 acc2[8];
        #pragma unroll
        for (int ct = 0; ct < 8; ++ct) acc2[ct] = (f32x4){0.f, 0.f, 0.f, 0.f};
        #pragma unroll
        for (int ct = 0; ct < 8; ++ct)
            #pragma unroll
            for (int ks = 0; ks < 4; ++ks) {
                bf16x8 bf = *(const bf16x8*)&sW[CH * CH + (ct * 16 + l16) * CH + ks * 32 + quad * 8];
                acc2[ct] = __builtin_amdgcn_mfma_f32_16x16x32_bf16(af2[ks], bf, acc2[ct], 0, 0, 0);
            }
        #pragma unroll
        for (int ct = 0; ct < 8; ++ct) {
            int col = ct * 16 + l16;
            float sc = scale2[col], sh = shift2[col];
            #pragma unroll
            for (int r = 0; r < 4; ++r) {
                int row = r0 + quad * 4 + r;
                if (row < N_NODES)
                    Out[(size_t)row * CH + col] = f2b(fmaxf(acc2[ct][r] * sc + sh, 0.f));
            }
        }
    }
}

// ---------------- pooling + classifier ----------------
__global__ __launch_bounds__(128) void pool_kernel(const ushort_t* __restrict__ h,
                                                   const int* __restrict__ starts,
                                                   float* __restrict__ pooled) {
    int g = blockIdx.x / NSPLIT, s = blockIdx.x % NSPLIT;
    int c = threadIdx.x;
    int beg = starts[g], end = starts[g + 1];
    float sum = 0.f;
    for (int n = beg + s; n < end; n += NSPLIT)
        sum += b2f(h[(size_t)n * CH + c]);
    atomicAdd(&pooled[g * CH + c], sum);
}

__global__ __launch_bounds__(256) void cls_kernel(const float* __restrict__ pooled,
                                                  const float* __restrict__ Wc,
                                                  const float* __restrict__ bc,
                                                  float* __restrict__ out) {
    int i = blockIdx.x * blockDim.x + threadIdx.x;
    if (i >= N_GRAPHS * OUT_CH) return;
    int g = i / OUT_CH, o = i % OUT_CH;
    float s = bc[o];
    for (int k = 0; k < CH; ++k) s += pooled[g * CH + k] * Wc[k * OUT_CH + o];
    out[i] = s;
}

// ---------------- launch ----------------
extern "C" void kernel_launch(void* const* d_in, const int* in_sizes, int n_in,
                              void* d_out, int out_size, void* d_ws, size_t ws_size,
                              hipStream_t stream) {
    const float* x     = (const float*)d_in[0];
    const int*   eidx  = (const int*)d_in[1];
    const int*   batch = (const int*)d_in[2];
    const float* W1    = (const float*)d_in[3];
    const float* b1    = (const float*)d_in[4];
    const float* W2    = (const float*)d_in[5];
    const float* b2    = (const float*)d_in[6];
    const float* gamma = (const float*)d_in[7];
    const float* beta  = (const float*)d_in[8];
    const float* mean  = (const float*)d_in[9];
    const float* var   = (const float*)d_in[10];
    const float* Wc    = (const float*)d_in[11];
    const float* bc    = (const float*)d_in[12];
    float* out = (float*)d_out;

    const int* src = eidx;
    const int* dst = eidx + N_EDGES;

    char* w = (char*)d_ws;
    size_t off = 0;
    auto alloc = [&](size_t bytes) { void* p = w + off; off += (bytes + 255) & ~(size_t)255; return p; };
    int*      deg    = (int*)alloc(N_NODES * 4);
    int*      rowptr = (int*)alloc((N_NODES + 1) * 4);
    int*      esrc   = (int*)alloc(N_EDGES * 4);
    int*      bsum   = (int*)alloc(NCHUNK * 4);
    int*      boff   = (int*)alloc(NCHUNK * 4);
    int*      gcur   = (int*)alloc(NB * 4);
    int2*     gbuck  = (int2*)alloc((size_t)NB * BCAP * 8);
    int*      starts = (int*)alloc((N_GRAPHS + 1) * 4);
    ushort_t* Bh     = (ushort_t*)alloc((size_t)N_NODES * CH * 2);
    ushort_t* Bz     = (ushort_t*)alloc((size_t)N_NODES * CH * 2);
    ushort_t* Wt     = (ushort_t*)alloc((size_t)6 * CH * CH * 2);
    float*    scale  = (float*)alloc(6 * CH * 4);
    float*    shift  = (float*)alloc(6 * CH * 4);
    float*    pooled = (float*)alloc(N_GRAPHS * CH * 4);
    (void)ws_size; (void)n_in; (void)in_sizes; (void)out_size;

    const int n4 = (N_NODES * CH) / 4;
    cast_kernel<<<(n4 + 255) / 256, 256, 0, stream>>>((const float4*)x, (ushort4*)Bh, n4);
    hipMemsetAsync(deg, 0, N_NODES * 4, stream);
    hipMemsetAsync(gcur, 0, NB * 4, stream);
    hipMemsetAsync(pooled, 0, N_GRAPHS * CH * 4, stream);
    hist_kernel<<<(N_EDGES + 255) / 256, 256, 0, stream>>>(dst, deg);
    scan1_kernel<<<NCHUNK, 1024, 0, stream>>>(deg, rowptr, bsum);
    scan2_kernel<<<1, 64, 0, stream>>>(bsum, boff);
    scan3_kernel<<<NCHUNK, 1024, 0, stream>>>(rowptr, boff);
    bin_kernel<<<(N_EDGES + EPB - 1) / EPB, 256, 0, stream>>>(src, dst, gcur, gbuck);
    place_kernel<<<NB, 256, 0, stream>>>(gcur, gbuck, rowptr, esrc);
    starts_kernel<<<(N_NODES + 255) / 256, 256, 0, stream>>>(batch, starts);
    wprep_kernel<<<(6 * CH * CH + 255) / 256, 256, 0, stream>>>(W1, W2, Wt);
    eprep_kernel<<<(6 * CH + 255) / 256, 256, 0, stream>>>(b1, b2, gamma, beta, mean, var, scale, shift);

    const int agg_grid = (N_NODES + 3) / 4;
    const int mlp_grid = (N_NODES + 191) / 192;

    for (int i = 0; i < N_LAYERS; ++i) {
        agg_kernel<<<agg_grid, 256, 0, stream>>>((const unsigned*)Bh, rowptr, esrc,
                                                 (unsigned*)Bz);
        mlp_kernel<<<mlp_grid, 384, 0, stream>>>(Bz,
                                                 Wt + (size_t)i * CH * CH,
                                                 Wt + (size_t)(3 + i) * CH * CH,
                                                 shift + i * CH,
                                                 scale + (3 + i) * CH,
                                                 shift + (3 + i) * CH,
                                                 Bh);
    }

    pool_kernel<<<N_GRAPHS * NSPLIT, 128, 0, stream>>>(Bh, starts, pooled);
    cls_kernel<<<(N_GRAPHS * OUT_CH + 255) / 256, 256, 0, stream>>>(pooled, Wc, bc, out);
}

// Round 8
// 330.241 us; speedup vs baseline: 7.0720x; 1.2606x over previous
//
#include <hip/hip_runtime.h>

#define N_NODES 50000
#define N_EDGES 800000
#define CH 128
#define N_GRAPHS 128
#define N_LAYERS 3
#define OUT_CH 16
#define BN_EPS 1e-5f
#define NCHUNK ((N_NODES + 1023) / 1024)
#define NSPLIT 8
#define NB 196
#define BCAP 4608
#define EPB 4096
#define NTILES (N_NODES / 16)      // 3125, exact
#define SSTRIDE 20                 // strip k-row stride in halfwords (8B aligned, bank-spread)

typedef unsigned short ushort_t;
typedef __attribute__((ext_vector_type(8))) short bf16x8;
typedef __attribute__((ext_vector_type(4))) float f32x4;

__device__ inline ushort_t f2b(float f) {
    unsigned u = __float_as_uint(f);
    unsigned r = (u + 0x7fffu + ((u >> 16) & 1u)) >> 16;
    return (ushort_t)r;
}
__device__ inline float b2f(ushort_t b) { return __uint_as_float((unsigned)b << 16); }
__device__ inline float blo(unsigned u) { return __uint_as_float(u << 16); }
__device__ inline float bhi(unsigned u) { return __uint_as_float(u & 0xffff0000u); }

// ---------------- fp32 x -> bf16 flat [N][128] ----------------
__global__ __launch_bounds__(256) void cast_kernel(const float4* __restrict__ x,
                                                   ushort4* __restrict__ xb, int n4) {
    int i = blockIdx.x * blockDim.x + threadIdx.x;
    if (i >= n4) return;
    float4 v = x[i];
    ushort4 o;
    o.x = f2b(v.x); o.y = f2b(v.y); o.z = f2b(v.z); o.w = f2b(v.w);
    xb[i] = o;
}

// ---------------- CSR build ----------------
__global__ void hist_kernel(const int* __restrict__ dst, int* __restrict__ deg) {
    int i = blockIdx.x * blockDim.x + threadIdx.x;
    if (i < N_EDGES) atomicAdd(&deg[dst[i]], 1);
}

__global__ __launch_bounds__(1024) void scan1_kernel(const int* __restrict__ deg,
                                                     int* __restrict__ rowptr,
                                                     int* __restrict__ bsum) {
    __shared__ int sdata[1024];
    int t = threadIdx.x, base = blockIdx.x * 1024;
    int v = (base + t < N_NODES) ? deg[base + t] : 0;
    sdata[t] = v;
    __syncthreads();
    #pragma unroll
    for (int off = 1; off < 1024; off <<= 1) {
        int y = (t >= off) ? sdata[t - off] : 0;
        __syncthreads();
        sdata[t] += y;
        __syncthreads();
    }
    if (base + t < N_NODES) rowptr[base + t] = sdata[t] - v;
    if (t == 1023) bsum[blockIdx.x] = sdata[1023];
}

__global__ void scan2_kernel(const int* __restrict__ bsum, int* __restrict__ boff) {
    int lane = threadIdx.x;
    int v = (lane < NCHUNK) ? bsum[lane] : 0;
    int orig = v;
    #pragma unroll
    for (int off = 1; off < 64; off <<= 1) {
        int tv = __shfl_up(v, off);
        if (lane >= off) v += tv;
    }
    if (lane < NCHUNK) boff[lane] = v - orig;
}

__global__ __launch_bounds__(1024) void scan3_kernel(int* __restrict__ rowptr,
                                                     const int* __restrict__ boff) {
    int i = blockIdx.x * 1024 + threadIdx.x;
    if (i < N_NODES) rowptr[i] += boff[blockIdx.x];
    if (i == 0) rowptr[N_NODES] = N_EDGES;
}

__global__ __launch_bounds__(256) void bin_kernel(const int* __restrict__ src,
                                                  const int* __restrict__ dst,
                                                  int* __restrict__ gcur,
                                                  int2* __restrict__ gbuck) {
    __shared__ int lcnt[256];
    __shared__ int lpref[256];
    __shared__ int lpos[NB];
    __shared__ int lbase[NB];
    __shared__ int2 stage[EPB];
    int t = threadIdx.x;
    int e0 = blockIdx.x * EPB;
    int nloc = N_EDGES - e0; if (nloc > EPB) nloc = EPB;

    lcnt[t] = 0;
    __syncthreads();

    int2 ed[16];
    #pragma unroll
    for (int j = 0; j < 16; ++j) {
        int i = j * 256 + t;
        if (i < nloc) {
            ed[j].x = src[e0 + i];
            ed[j].y = dst[e0 + i];
            atomicAdd(&lcnt[ed[j].y >> 8], 1);
        } else ed[j].y = -1;
    }
    __syncthreads();
    int v = lcnt[t];
    lpref[t] = v;
    __syncthreads();
    for (int off = 1; off < 256; off <<= 1) {
        int y = (t >= off) ? lpref[t - off] : 0;
        __syncthreads();
        lpref[t] += y;
        __syncthreads();
    }
    int excl = lpref[t] - v;
    __syncthreads();
    lpref[t] = excl;
    if (t < NB) {
        lpos[t] = excl;
        lbase[t] = atomicAdd(&gcur[t], v);
    }
    __syncthreads();
    #pragma unroll
    for (int j = 0; j < 16; ++j) {
        if (ed[j].y >= 0) {
            int slot = atomicAdd(&lpos[ed[j].y >> 8], 1);
            stage[slot] = ed[j];
        }
    }
    __syncthreads();
    for (int i = t; i < nloc; i += 256) {
        int2 e = stage[i];
        int b = e.y >> 8;
        gbuck[(size_t)b * BCAP + lbase[b] + (i - lpref[b])] = e;
    }
}

__global__ __launch_bounds__(256) void place_kernel(const int* __restrict__ gcur,
                                                    const int2* __restrict__ gbuck,
                                                    const int* __restrict__ rowptr,
                                                    int* __restrict__ esrc) {
    __shared__ int ssrc[BCAP];
    __shared__ unsigned char sd[BCAP];
    __shared__ int outS[BCAP];
    __shared__ int cnt[256], pref[256], cur[256];
    int b = blockIdx.x, t = threadIdx.x;
    int nb = gcur[b];
    cnt[t] = 0;
    __syncthreads();
    for (int i = t; i < nb; i += 256) {
        int2 e = gbuck[(size_t)b * BCAP + i];
        ssrc[i] = e.x;
        int dl = e.y & 255;
        sd[i] = (unsigned char)dl;
        atomicAdd(&cnt[dl], 1);
    }
    __syncthreads();
    int v = cnt[t];
    pref[t] = v;
    __syncthreads();
    for (int off = 1; off < 256; off <<= 1) {
        int y = (t >= off) ? pref[t - off] : 0;
        __syncthreads();
        pref[t] += y;
        __syncthreads();
    }
    int excl = pref[t] - v;
    __syncthreads();
    pref[t] = excl;
    cur[t] = 0;
    __syncthreads();
    for (int i = t; i < nb; i += 256) {
        int dl = sd[i];
        int p = pref[dl] + atomicAdd(&cur[dl], 1);
        outS[p] = ssrc[i];
    }
    __syncthreads();
    int base = rowptr[b << 8];
    for (int i = t; i < nb; i += 256)
        esrc[base + i] = outS[i];
}

__global__ void starts_kernel(const int* __restrict__ batch, int* __restrict__ starts) {
    int i = blockIdx.x * blockDim.x + threadIdx.x;
    if (i >= N_NODES) return;
    int b = batch[i];
    if (i == 0) {
        for (int g = 0; g <= b; ++g) starts[g] = 0;
    } else {
        int pb = batch[i - 1];
        for (int g = pb + 1; g <= b; ++g) starts[g] = i;
    }
    if (i == N_NODES - 1) {
        for (int g = b + 1; g <= N_GRAPHS; ++g) starts[g] = N_NODES;
    }
}

// ---------------- weight prep: pre-swizzled MFMA B-fragments ----------------
// Per matrix (16384 halfwords): frag layout [ct(8)][ks(4)][lane(64)][j(8)],
// element = W[k][n] with n = ct*16 + (lane&15), k = ks*32 + (lane>>4)*8 + j.
__global__ __launch_bounds__(256) void wprep_kernel(const float* __restrict__ W1,
                                                    const float* __restrict__ W2,
                                                    ushort_t* __restrict__ Wt) {
    int i = blockIdx.x * blockDim.x + threadIdx.x;
    if (i >= 6 * CH * CH) return;
    int mat = i >> 14, r = i & 16383;
    int j = r & 7, b = r >> 3;           // b = (ct*4+ks)*64 + lane
    int lane = b & 63, cs = b >> 6;
    int ct = cs >> 2, ks = cs & 3;
    int n = ct * 16 + (lane & 15);
    int k = ks * 32 + (lane >> 4) * 8 + j;
    const float* Wsrc = (mat < 3) ? (W1 + (size_t)mat * CH * CH)
                                  : (W2 + (size_t)(mat - 3) * CH * CH);
    Wt[i] = f2b(Wsrc[k * CH + n]);
}

__global__ void eprep_kernel(const float* __restrict__ b1, const float* __restrict__ b2,
                             const float* __restrict__ gamma, const float* __restrict__ beta,
                             const float* __restrict__ mean, const float* __restrict__ var,
                             float* __restrict__ scale, float* __restrict__ shift) {
    int i = blockIdx.x * blockDim.x + threadIdx.x;
    if (i >= 6 * CH) return;
    int mat = i / CH, c = i % CH;
    if (mat < 3) {
        scale[i] = 1.f;
        shift[i] = b1[mat * CH + c];
    } else {
        int l = mat - 3;
        float inv = gamma[l * CH + c] * rsqrtf(var[l * CH + c] + BN_EPS);
        scale[i] = inv;
        shift[i] = (b2[l * CH + c] - mean[l * CH + c]) * inv + beta[l * CH + c];
    }
}

// ---------------- aggregation: pull, wave/node, 16-deep gather unroll ----------------
__global__ __launch_bounds__(256) void agg_kernel(const unsigned* __restrict__ h2,
                                                  const int* __restrict__ rowptr,
                                                  const int* __restrict__ esrc,
                                                  unsigned* __restrict__ z2) {
    int wid = (blockIdx.x * 256 + threadIdx.x) >> 6;
    int lane = threadIdx.x & 63;
    if (wid >= N_NODES) return;
    unsigned self = h2[(size_t)wid * 64 + lane];
    float ax = blo(self), ay = bhi(self);
    int e = rowptr[wid], end = rowptr[wid + 1];
    for (; e + 16 <= end; e += 16) {
        unsigned u[16];
        #pragma unroll
        for (int j = 0; j < 16; ++j) {
            int s = esrc[e + j];
            u[j] = h2[(size_t)s * 64 + lane];
        }
        #pragma unroll
        for (int j = 0; j < 16; ++j) { ax += blo(u[j]); ay += bhi(u[j]); }
    }
    for (; e + 8 <= end; e += 8) {
        unsigned u[8];
        #pragma unroll
        for (int j = 0; j < 8; ++j) {
            int s = esrc[e + j];
            u[j] = h2[(size_t)s * 64 + lane];
        }
        #pragma unroll
        for (int j = 0; j < 8; ++j) { ax += blo(u[j]); ay += bhi(u[j]); }
    }
    for (; e + 4 <= end; e += 4) {
        unsigned u[4];
        #pragma unroll
        for (int j = 0; j < 4; ++j) {
            int s = esrc[e + j];
            u[j] = h2[(size_t)s * 64 + lane];
        }
        #pragma unroll
        for (int j = 0; j < 4; ++j) { ax += blo(u[j]); ay += bhi(u[j]); }
    }
    for (; e < end; ++e) {
        unsigned u = h2[(size_t)esrc[e] * 64 + lane];
        ax += blo(u); ay += bhi(u);
    }
    z2[(size_t)wid * 64 + lane] = ((unsigned)f2b(ay) << 16) | (unsigned)f2b(ax);
}

// ---------------- fused MLP: grid 256 x 512 thr; conflict-free LDS ----------------
// sW: pre-swizzled fragments, lane-contiguous reads. Strip: [k][m] layout,
// stride 20 halfwords -> b64 writes (4 row-contig), u16 reads, both ~conflict-free.
__global__ __launch_bounds__(512) void mlp_kernel(const ushort_t* __restrict__ A,
                                                  const ushort_t* __restrict__ Wf1,
                                                  const ushort_t* __restrict__ Wf2,
                                                  const float* __restrict__ shift1,
                                                  const float* __restrict__ scale2,
                                                  const float* __restrict__ shift2,
                                                  ushort_t* __restrict__ Out) {
    __shared__ ushort_t sW1[CH * CH];          // 32 KB fragments
    __shared__ ushort_t sW2[CH * CH];          // 32 KB
    __shared__ ushort_t sS[8][CH * SSTRIDE];   // 8 x 5 KB strips

    int t = threadIdx.x;
    int wave = t >> 6, lane = t & 63;
    int quad = lane >> 4, l16 = lane & 15;

    {   // stage fragment matrices, straight copy (conflict-free)
        const uint4* g1 = (const uint4*)Wf1;
        const uint4* g2 = (const uint4*)Wf2;
        uint4* s1 = (uint4*)sW1;
        uint4* s2 = (uint4*)sW2;
        for (int i = t; i < 2048; i += 512) { s1[i] = g1[i]; s2[i] = g2[i]; }
    }
    __syncthreads();

    const bf16x8* w1f = (const bf16x8*)sW1;
    const bf16x8* w2f = (const bf16x8*)sW2;
    int wg = blockIdx.x * 8 + wave;            // global wave id, 0..2047

    for (int it = 0; it < 2; ++it) {
        int tile = wg + 2048 * it;
        if (tile >= NTILES) break;
        int arow = tile * 16 + l16;            // < 50000 always (3125*16 exact)

        bf16x8 af[4];
        #pragma unroll
        for (int ks = 0; ks < 4; ++ks)
            af[ks] = *(const bf16x8*)(A + (size_t)arow * CH + ks * 32 + quad * 8);

        // ---- GEMM1 ----
        f32x4 acc[8];
        #pragma unroll
        for (int ct = 0; ct < 8; ++ct) acc[ct] = (f32x4){0.f, 0.f, 0.f, 0.f};
        #pragma unroll
        for (int ct = 0; ct < 8; ++ct)
            #pragma unroll
            for (int ks = 0; ks < 4; ++ks)
                acc[ct] = __builtin_amdgcn_mfma_f32_16x16x32_bf16(
                    af[ks], w1f[(ct * 4 + ks) * 64 + lane], acc[ct], 0, 0, 0);

        // ---- epilogue1 -> strip [k][m], b64 writes ----
        #pragma unroll
        for (int ct = 0; ct < 8; ++ct) {
            int k = ct * 16 + l16;
            float sh = shift1[k];
            uint2 p;
            p.x = ((unsigned)f2b(fmaxf(acc[ct][1] + sh, 0.f)) << 16)
                |  (unsigned)f2b(fmaxf(acc[ct][0] + sh, 0.f));
            p.y = ((unsigned)f2b(fmaxf(acc[ct][3] + sh, 0.f)) << 16)
                |  (unsigned)f2b(fmaxf(acc[ct][2] + sh, 0.f));
            *(uint2*)&sS[wave][k * SSTRIDE + quad * 4] = p;
        }

        // ---- A-frag2 from strip (u16 reads, same-wave ordering) ----
        bf16x8 af2[4];
        #pragma unroll
        for (int ks = 0; ks < 4; ++ks)
            #pragma unroll
            for (int j = 0; j < 8; ++j)
                af2[ks][j] = (short)sS[wave][(ks * 32 + quad * 8 + j) * SSTRIDE + l16];

        // ---- GEMM2 ----
        f32x4 acc2[8];
        #pragma unroll
        for (int ct = 0; ct < 8; ++ct) acc2[ct] = (f32x4){0.f, 0.f, 0.f, 0.f};
        #pragma unroll
        for (int ct = 0; ct < 8; ++ct)
            #pragma unroll
            for (int ks = 0; ks < 4; ++ks)
                acc2[ct] = __builtin_amdgcn_mfma_f32_16x16x32_bf16(
                    af2[ks], w2f[(ct * 4 + ks) * 64 + lane], acc2[ct], 0, 0, 0);

        // ---- epilogue2 -> global ----
        int row0 = tile * 16;
        #pragma unroll
        for (int ct = 0; ct < 8; ++ct) {
            int col = ct * 16 + l16;
            float sc = scale2[col], sh = shift2[col];
            #pragma unroll
            for (int r = 0; r < 4; ++r) {
                int row = row0 + quad * 4 + r;
                Out[(size_t)row * CH + col] = f2b(fmaxf(acc2[ct][r] * sc + sh, 0.f));
            }
        }
    }
}

// ---------------- pooling + classifier ----------------
__global__ __launch_bounds__(128) void pool_kernel(const ushort_t* __restrict__ h,
                                                   const int* __restrict__ starts,
                                                   float* __restrict__ pooled) {
    int g = blockIdx.x / NSPLIT, s = blockIdx.x % NSPLIT;
    int c = threadIdx.x;
    int beg = starts[g], end = starts[g + 1];
    float sum = 0.f;
    for (int n = beg + s; n < end; n += NSPLIT)
        sum += b2f(h[(size_t)n * CH + c]);
    atomicAdd(&pooled[g * CH + c], sum);
}

__global__ __launch_bounds__(256) void cls_kernel(const float* __restrict__ pooled,
                                                  const float* __restrict__ Wc,
                                                  const float* __restrict__ bc,
                                                  float* __restrict__ out) {
    int i = blockIdx.x * blockDim.x + threadIdx.x;
    if (i >= N_GRAPHS * OUT_CH) return;
    int g = i / OUT_CH, o = i % OUT_CH;
    float s = bc[o];
    for (int k = 0; k < CH; ++k) s += pooled[g * CH + k] * Wc[k * OUT_CH + o];
    out[i] = s;
}

// ---------------- launch ----------------
extern "C" void kernel_launch(void* const* d_in, const int* in_sizes, int n_in,
                              void* d_out, int out_size, void* d_ws, size_t ws_size,
                              hipStream_t stream) {
    const float* x     = (const float*)d_in[0];
    const int*   eidx  = (const int*)d_in[1];
    const int*   batch = (const int*)d_in[2];
    const float* W1    = (const float*)d_in[3];
    const float* b1    = (const float*)d_in[4];
    const float* W2    = (const float*)d_in[5];
    const float* b2    = (const float*)d_in[6];
    const float* gamma = (const float*)d_in[7];
    const float* beta  = (const float*)d_in[8];
    const float* mean  = (const float*)d_in[9];
    const float* var   = (const float*)d_in[10];
    const float* Wc    = (const float*)d_in[11];
    const float* bc    = (const float*)d_in[12];
    float* out = (float*)d_out;

    const int* src = eidx;
    const int* dst = eidx + N_EDGES;

    char* w = (char*)d_ws;
    size_t off = 0;
    auto alloc = [&](size_t bytes) { void* p = w + off; off += (bytes + 255) & ~(size_t)255; return p; };
    int*      deg    = (int*)alloc(N_NODES * 4);
    int*      rowptr = (int*)alloc((N_NODES + 1) * 4);
    int*      esrc   = (int*)alloc(N_EDGES * 4);
    int*      bsum   = (int*)alloc(NCHUNK * 4);
    int*      boff   = (int*)alloc(NCHUNK * 4);
    int*      gcur   = (int*)alloc(NB * 4);
    int2*     gbuck  = (int2*)alloc((size_t)NB * BCAP * 8);
    int*      starts = (int*)alloc((N_GRAPHS + 1) * 4);
    ushort_t* Bh     = (ushort_t*)alloc((size_t)N_NODES * CH * 2);
    ushort_t* Bz     = (ushort_t*)alloc((size_t)N_NODES * CH * 2);
    ushort_t* Wt     = (ushort_t*)alloc((size_t)6 * CH * CH * 2);
    float*    scale  = (float*)alloc(6 * CH * 4);
    float*    shift  = (float*)alloc(6 * CH * 4);
    float*    pooled = (float*)alloc(N_GRAPHS * CH * 4);
    (void)ws_size; (void)n_in; (void)in_sizes; (void)out_size;

    const int n4 = (N_NODES * CH) / 4;
    cast_kernel<<<(n4 + 255) / 256, 256, 0, stream>>>((const float4*)x, (ushort4*)Bh, n4);
    hipMemsetAsync(deg, 0, N_NODES * 4, stream);
    hipMemsetAsync(gcur, 0, NB * 4, stream);
    hipMemsetAsync(pooled, 0, N_GRAPHS * CH * 4, stream);
    hist_kernel<<<(N_EDGES + 255) / 256, 256, 0, stream>>>(dst, deg);
    scan1_kernel<<<NCHUNK, 1024, 0, stream>>>(deg, rowptr, bsum);
    scan2_kernel<<<1, 64, 0, stream>>>(bsum, boff);
    scan3_kernel<<<NCHUNK, 1024, 0, stream>>>(rowptr, boff);
    bin_kernel<<<(N_EDGES + EPB - 1) / EPB, 256, 0, stream>>>(src, dst, gcur, gbuck);
    place_kernel<<<NB, 256, 0, stream>>>(gcur, gbuck, rowptr, esrc);
    starts_kernel<<<(N_NODES + 255) / 256, 256, 0, stream>>>(batch, starts);
    wprep_kernel<<<(6 * CH * CH + 255) / 256, 256, 0, stream>>>(W1, W2, Wt);
    eprep_kernel<<<(6 * CH + 255) / 256, 256, 0, stream>>>(b1, b2, gamma, beta, mean, var, scale, shift);

    const int agg_grid = (N_NODES + 3) / 4;

    for (int i = 0; i < N_LAYERS; ++i) {
        agg_kernel<<<agg_grid, 256, 0, stream>>>((const unsigned*)Bh, rowptr, esrc,
                                                 (unsigned*)Bz);
        mlp_kernel<<<256, 512, 0, stream>>>(Bz,
                                            Wt + (size_t)i * CH * CH,
                                            Wt + (size_t)(3 + i) * CH * CH,
                                            shift + i * CH,
                                            scale + (3 + i) * CH,
                                            shift + (3 + i) * CH,
                                            Bh);
    }

    pool_kernel<<<N_GRAPHS * NSPLIT, 128, 0, stream>>>(Bh, starts, pooled);
    cls_kernel<<<(N_GRAPHS * OUT_CH + 255) / 256, 256, 0, stream>>>(pooled, Wc, bc, out);
}

// Round 9
// 278.630 us; speedup vs baseline: 8.3820x; 1.1852x over previous
//
#include <hip/hip_runtime.h>

#define N_NODES 50000
#define N_EDGES 800000
#define CH 128
#define N_GRAPHS 128
#define N_LAYERS 3
#define OUT_CH 16
#define BN_EPS 1e-5f
#define NSPLIT 16
#define NB 196            // dst>>8 buckets (256 dsts each)
#define BCAP 4608
#define EPB 4096
#define NTILES (N_NODES / 16)      // 3125 exact
#define SSTRIDE 20

typedef unsigned short ushort_t;
typedef __attribute__((ext_vector_type(8))) short bf16x8;
typedef __attribute__((ext_vector_type(4))) float f32x4;

__device__ inline ushort_t f2b(float f) {
    unsigned u = __float_as_uint(f);
    unsigned r = (u + 0x7fffu + ((u >> 16) & 1u)) >> 16;
    return (ushort_t)r;
}
__device__ inline float b2f(ushort_t b) { return __uint_as_float((unsigned)b << 16); }
__device__ inline float blo(unsigned u) { return __uint_as_float(u << 16); }
__device__ inline float bhi(unsigned u) { return __uint_as_float(u & 0xffff0000u); }

// ---------------- fp32 x -> bf16 flat [N][128]; also zeros gcur ----------------
__global__ __launch_bounds__(256) void cast_kernel(const float4* __restrict__ x,
                                                   ushort4* __restrict__ xb, int n4,
                                                   int* __restrict__ gcur) {
    int i = blockIdx.x * blockDim.x + threadIdx.x;
    if (i < NB) gcur[i] = 0;
    if (i >= n4) return;
    float4 v = x[i];
    ushort4 o;
    o.x = f2b(v.x); o.y = f2b(v.y); o.z = f2b(v.z); o.w = f2b(v.w);
    xb[i] = o;
}

// ---------------- edge binning: pack = src | (dst&255)<<16, bucket = dst>>8 ----------------
__global__ __launch_bounds__(256) void bin_kernel(const int* __restrict__ src,
                                                  const int* __restrict__ dst,
                                                  int* __restrict__ gcur,
                                                  unsigned* __restrict__ gbuck) {
    __shared__ int lcnt[256];
    __shared__ int lpref[256];
    __shared__ int lpos[NB];
    __shared__ int lbase[NB];
    __shared__ unsigned stage[EPB];
    __shared__ unsigned char sbk[EPB];
    int t = threadIdx.x;
    int e0 = blockIdx.x * EPB;
    int nloc = N_EDGES - e0; if (nloc > EPB) nloc = EPB;

    lcnt[t] = 0;
    __syncthreads();

    int2 ed[16];
    #pragma unroll
    for (int j = 0; j < 16; ++j) {
        int i = j * 256 + t;
        if (i < nloc) {
            ed[j].x = src[e0 + i];
            ed[j].y = dst[e0 + i];
            atomicAdd(&lcnt[ed[j].y >> 8], 1);
        } else ed[j].y = -1;
    }
    __syncthreads();
    int v = lcnt[t];
    lpref[t] = v;
    __syncthreads();
    for (int off = 1; off < 256; off <<= 1) {
        int y = (t >= off) ? lpref[t - off] : 0;
        __syncthreads();
        lpref[t] += y;
        __syncthreads();
    }
    int excl = lpref[t] - v;
    __syncthreads();
    lpref[t] = excl;
    if (t < NB) {
        lpos[t] = excl;
        lbase[t] = atomicAdd(&gcur[t], v);
    }
    __syncthreads();
    #pragma unroll
    for (int j = 0; j < 16; ++j) {
        if (ed[j].y >= 0) {
            int b = ed[j].y >> 8;
            int slot = atomicAdd(&lpos[b], 1);
            stage[slot] = (unsigned)ed[j].x | ((unsigned)(ed[j].y & 255) << 16);
            sbk[slot] = (unsigned char)b;
        }
    }
    __syncthreads();
    for (int i = t; i < nloc; i += 256) {
        int b = sbk[i];
        gbuck[(size_t)b * BCAP + lbase[b] + (i - lpref[b])] = stage[i];
    }
}

// ---------------- exclusive scan over 196 bucket sizes ----------------
__global__ __launch_bounds__(256) void bscan_kernel(const int* __restrict__ gcur,
                                                    int* __restrict__ gbase) {
    __shared__ int s[256];
    int t = threadIdx.x;
    int v = (t < NB) ? gcur[t] : 0;
    s[t] = v;
    __syncthreads();
    for (int off = 1; off < 256; off <<= 1) {
        int y = (t >= off) ? s[t - off] : 0;
        __syncthreads();
        s[t] += y;
        __syncthreads();
    }
    if (t < NB) gbase[t] = s[t] - v;
}

// ---------------- per-bucket sort to CSR slots; also writes rowptr ----------------
__global__ __launch_bounds__(256) void place_kernel(const int* __restrict__ gcur,
                                                    const int* __restrict__ gbase,
                                                    const unsigned* __restrict__ gbuck,
                                                    int* __restrict__ rowptr,
                                                    int* __restrict__ esrc) {
    __shared__ ushort_t ssrc[BCAP];
    __shared__ unsigned char sd[BCAP];
    __shared__ int outS[BCAP];
    __shared__ int cnt[256], pref[256], cur[256];
    int b = blockIdx.x, t = threadIdx.x;
    int nb = gcur[b];
    int base = gbase[b];
    cnt[t] = 0;
    __syncthreads();
    for (int i = t; i < nb; i += 256) {
        unsigned p = gbuck[(size_t)b * BCAP + i];
        ssrc[i] = (ushort_t)(p & 0xffffu);
        int dl = (p >> 16) & 0xff;
        sd[i] = (unsigned char)dl;
        atomicAdd(&cnt[dl], 1);
    }
    __syncthreads();
    int v = cnt[t];
    pref[t] = v;
    __syncthreads();
    for (int off = 1; off < 256; off <<= 1) {
        int y = (t >= off) ? pref[t - off] : 0;
        __syncthreads();
        pref[t] += y;
        __syncthreads();
    }
    int excl = pref[t] - v;
    __syncthreads();
    pref[t] = excl;
    cur[t] = 0;
    // rowptr for this bucket's 256 nodes
    int idx = (b << 8) + t;
    if (idx < N_NODES) rowptr[idx] = base + excl;
    if (b == NB - 1 && t == 0) rowptr[N_NODES] = N_EDGES;
    __syncthreads();
    for (int i = t; i < nb; i += 256) {
        int dl = sd[i];
        int p = pref[dl] + atomicAdd(&cur[dl], 1);
        outS[p] = ssrc[i];
    }
    __syncthreads();
    for (int i = t; i < nb; i += 256)
        esrc[base + i] = outS[i];
}

// ---------------- graph starts; also zeros pooled ----------------
__global__ void starts_kernel(const int* __restrict__ batch, int* __restrict__ starts,
                              float* __restrict__ pooled) {
    int i = blockIdx.x * blockDim.x + threadIdx.x;
    if (i < N_GRAPHS * CH) pooled[i] = 0.f;
    if (i >= N_NODES) return;
    int b = batch[i];
    if (i == 0) {
        for (int g = 0; g <= b; ++g) starts[g] = 0;
    } else {
        int pb = batch[i - 1];
        for (int g = pb + 1; g <= b; ++g) starts[g] = i;
    }
    if (i == N_NODES - 1) {
        for (int g = b + 1; g <= N_GRAPHS; ++g) starts[g] = N_NODES;
    }
}

// ---------------- merged weight-fragment + epilogue prep ----------------
// Weights: per matrix frag layout [ct(8)][ks(4)][lane(64)][j(8)];
// element = W[k][n], n = ct*16+(lane&15), k = ks*32+(lane>>4)*8+j.
__global__ __launch_bounds__(256) void prep_kernel(const float* __restrict__ W1,
                                                   const float* __restrict__ W2,
                                                   ushort_t* __restrict__ Wt,
                                                   const float* __restrict__ b1,
                                                   const float* __restrict__ b2,
                                                   const float* __restrict__ gamma,
                                                   const float* __restrict__ beta,
                                                   const float* __restrict__ mean,
                                                   const float* __restrict__ var,
                                                   float* __restrict__ scale,
                                                   float* __restrict__ shift) {
    int i = blockIdx.x * blockDim.x + threadIdx.x;
    if (i < 6 * CH * CH) {
        int mat = i >> 14, r = i & 16383;
        int j = r & 7, bb = r >> 3;
        int lane = bb & 63, cs = bb >> 6;
        int ct = cs >> 2, ks = cs & 3;
        int n = ct * 16 + (lane & 15);
        int k = ks * 32 + (lane >> 4) * 8 + j;
        const float* Wsrc = (mat < 3) ? (W1 + (size_t)mat * CH * CH)
                                      : (W2 + (size_t)(mat - 3) * CH * CH);
        Wt[i] = f2b(Wsrc[k * CH + n]);
    } else {
        int e = i - 6 * CH * CH;
        if (e >= 6 * CH) return;
        int mat = e / CH, c = e % CH;
        if (mat < 3) {
            scale[e] = 1.f;
            shift[e] = b1[mat * CH + c];
        } else {
            int l = mat - 3;
            float inv = gamma[l * CH + c] * rsqrtf(var[l * CH + c] + BN_EPS);
            scale[e] = inv;
            shift[e] = (b2[l * CH + c] - mean[l * CH + c]) * inv + beta[l * CH + c];
        }
    }
}

// ---------------- aggregation: pull, wave/node, 16-deep gather unroll ----------------
__global__ __launch_bounds__(256) void agg_kernel(const unsigned* __restrict__ h2,
                                                  const int* __restrict__ rowptr,
                                                  const int* __restrict__ esrc,
                                                  unsigned* __restrict__ z2) {
    int wid = (blockIdx.x * 256 + threadIdx.x) >> 6;
    int lane = threadIdx.x & 63;
    if (wid >= N_NODES) return;
    unsigned self = h2[(size_t)wid * 64 + lane];
    float ax = blo(self), ay = bhi(self);
    int e = rowptr[wid], end = rowptr[wid + 1];
    for (; e + 16 <= end; e += 16) {
        unsigned u[16];
        #pragma unroll
        for (int j = 0; j < 16; ++j) {
            int s = esrc[e + j];
            u[j] = h2[(size_t)s * 64 + lane];
        }
        #pragma unroll
        for (int j = 0; j < 16; ++j) { ax += blo(u[j]); ay += bhi(u[j]); }
    }
    for (; e + 8 <= end; e += 8) {
        unsigned u[8];
        #pragma unroll
        for (int j = 0; j < 8; ++j) {
            int s = esrc[e + j];
            u[j] = h2[(size_t)s * 64 + lane];
        }
        #pragma unroll
        for (int j = 0; j < 8; ++j) { ax += blo(u[j]); ay += bhi(u[j]); }
    }
    for (; e + 4 <= end; e += 4) {
        unsigned u[4];
        #pragma unroll
        for (int j = 0; j < 4; ++j) {
            int s = esrc[e + j];
            u[j] = h2[(size_t)s * 64 + lane];
        }
        #pragma unroll
        for (int j = 0; j < 4; ++j) { ax += blo(u[j]); ay += bhi(u[j]); }
    }
    for (; e < end; ++e) {
        unsigned u = h2[(size_t)esrc[e] * 64 + lane];
        ax += blo(u); ay += bhi(u);
    }
    z2[(size_t)wid * 64 + lane] = ((unsigned)f2b(ay) << 16) | (unsigned)f2b(ax);
}

// ---------------- fused MLP (R8, conflict-free) ----------------
__global__ __launch_bounds__(512) void mlp_kernel(const ushort_t* __restrict__ A,
                                                  const ushort_t* __restrict__ Wf1,
                                                  const ushort_t* __restrict__ Wf2,
                                                  const float* __restrict__ shift1,
                                                  const float* __restrict__ scale2,
                                                  const float* __restrict__ shift2,
                                                  ushort_t* __restrict__ Out) {
    __shared__ ushort_t sW1[CH * CH];
    __shared__ ushort_t sW2[CH * CH];
    __shared__ ushort_t sS[8][CH * SSTRIDE];

    int t = threadIdx.x;
    int wave = t >> 6, lane = t & 63;
    int quad = lane >> 4, l16 = lane & 15;

    {
        const uint4* g1 = (const uint4*)Wf1;
        const uint4* g2 = (const uint4*)Wf2;
        uint4* s1 = (uint4*)sW1;
        uint4* s2 = (uint4*)sW2;
        for (int i = t; i < 2048; i += 512) { s1[i] = g1[i]; s2[i] = g2[i]; }
    }
    __syncthreads();

    const bf16x8* w1f = (const bf16x8*)sW1;
    const bf16x8* w2f = (const bf16x8*)sW2;
    int wg = blockIdx.x * 8 + wave;

    for (int it = 0; it < 2; ++it) {
        int tile = wg + 2048 * it;
        if (tile >= NTILES) break;
        int arow = tile * 16 + l16;

        bf16x8 af[4];
        #pragma unroll
        for (int ks = 0; ks < 4; ++ks)
            af[ks] = *(const bf16x8*)(A + (size_t)arow * CH + ks * 32 + quad * 8);

        f32x4 acc[8];
        #pragma unroll
        for (int ct = 0; ct < 8; ++ct) acc[ct] = (f32x4){0.f, 0.f, 0.f, 0.f};
        #pragma unroll
        for (int ct = 0; ct < 8; ++ct)
            #pragma unroll
            for (int ks = 0; ks < 4; ++ks)
                acc[ct] = __builtin_amdgcn_mfma_f32_16x16x32_bf16(
                    af[ks], w1f[(ct * 4 + ks) * 64 + lane], acc[ct], 0, 0, 0);

        #pragma unroll
        for (int ct = 0; ct < 8; ++ct) {
            int k = ct * 16 + l16;
            float sh = shift1[k];
            uint2 p;
            p.x = ((unsigned)f2b(fmaxf(acc[ct][1] + sh, 0.f)) << 16)
                |  (unsigned)f2b(fmaxf(acc[ct][0] + sh, 0.f));
            p.y = ((unsigned)f2b(fmaxf(acc[ct][3] + sh, 0.f)) << 16)
                |  (unsigned)f2b(fmaxf(acc[ct][2] + sh, 0.f));
            *(uint2*)&sS[wave][k * SSTRIDE + quad * 4] = p;
        }

        bf16x8 af2[4];
        #pragma unroll
        for (int ks = 0; ks < 4; ++ks)
            #pragma unroll
            for (int j = 0; j < 8; ++j)
                af2[ks][j] = (short)sS[wave][(ks * 32 + quad * 8 + j) * SSTRIDE + l16];

        f32x4 acc2[8];
        #pragma unroll
        for (int ct = 0; ct < 8; ++ct) acc2[ct] = (f32x4){0.f, 0.f, 0.f, 0.f};
        #pragma unroll
        for (int ct = 0; ct < 8; ++ct)
            #pragma unroll
            for (int ks = 0; ks < 4; ++ks)
                acc2[ct] = __builtin_amdgcn_mfma_f32_16x16x32_bf16(
                    af2[ks], w2f[(ct * 4 + ks) * 64 + lane], acc2[ct], 0, 0, 0);

        int row0 = tile * 16;
        #pragma unroll
        for (int ct = 0; ct < 8; ++ct) {
            int col = ct * 16 + l16;
            float sc = scale2[col], sh = shift2[col];
            #pragma unroll
            for (int r = 0; r < 4; ++r) {
                int row = row0 + quad * 4 + r;
                Out[(size_t)row * CH + col] = f2b(fmaxf(acc2[ct][r] * sc + sh, 0.f));
            }
        }
    }
}

// ---------------- pooling (dword reads, 16 splits) + classifier ----------------
__global__ __launch_bounds__(64) void pool_kernel(const unsigned* __restrict__ h2,
                                                  const int* __restrict__ starts,
                                                  float* __restrict__ pooled) {
    int g = blockIdx.x >> 4, s = blockIdx.x & 15;
    int c = threadIdx.x;   // dword channel pair
    int beg = starts[g], end = starts[g + 1];
    float s0 = 0.f, s1 = 0.f;
    for (int n = beg + s; n < end; n += NSPLIT) {
        unsigned u = h2[(size_t)n * 64 + c];
        s0 += blo(u); s1 += bhi(u);
    }
    atomicAdd(&pooled[g * CH + 2 * c], s0);
    atomicAdd(&pooled[g * CH + 2 * c + 1], s1);
}

__global__ __launch_bounds__(256) void cls_kernel(const float* __restrict__ pooled,
                                                  const float* __restrict__ Wc,
                                                  const float* __restrict__ bc,
                                                  float* __restrict__ out) {
    int i = blockIdx.x * blockDim.x + threadIdx.x;
    if (i >= N_GRAPHS * OUT_CH) return;
    int g = i / OUT_CH, o = i % OUT_CH;
    float s = bc[o];
    for (int k = 0; k < CH; ++k) s += pooled[g * CH + k] * Wc[k * OUT_CH + o];
    out[i] = s;
}

// ---------------- launch ----------------
extern "C" void kernel_launch(void* const* d_in, const int* in_sizes, int n_in,
                              void* d_out, int out_size, void* d_ws, size_t ws_size,
                              hipStream_t stream) {
    const float* x     = (const float*)d_in[0];
    const int*   eidx  = (const int*)d_in[1];
    const int*   batch = (const int*)d_in[2];
    const float* W1    = (const float*)d_in[3];
    const float* b1    = (const float*)d_in[4];
    const float* W2    = (const float*)d_in[5];
    const float* b2    = (const float*)d_in[6];
    const float* gamma = (const float*)d_in[7];
    const float* beta  = (const float*)d_in[8];
    const float* mean  = (const float*)d_in[9];
    const float* var   = (const float*)d_in[10];
    const float* Wc    = (const float*)d_in[11];
    const float* bc    = (const float*)d_in[12];
    float* out = (float*)d_out;

    const int* src = eidx;
    const int* dst = eidx + N_EDGES;

    char* w = (char*)d_ws;
    size_t off = 0;
    auto alloc = [&](size_t bytes) { void* p = w + off; off += (bytes + 255) & ~(size_t)255; return p; };
    int*      gcur   = (int*)alloc(NB * 4);
    int*      gbase  = (int*)alloc(NB * 4);
    unsigned* gbuck  = (unsigned*)alloc((size_t)NB * BCAP * 4);
    int*      rowptr = (int*)alloc((N_NODES + 1) * 4);
    int*      esrc   = (int*)alloc(N_EDGES * 4);
    int*      starts = (int*)alloc((N_GRAPHS + 1) * 4);
    ushort_t* Bh     = (ushort_t*)alloc((size_t)N_NODES * CH * 2);
    ushort_t* Bz     = (ushort_t*)alloc((size_t)N_NODES * CH * 2);
    ushort_t* Wt     = (ushort_t*)alloc((size_t)6 * CH * CH * 2);
    float*    scale  = (float*)alloc(6 * CH * 4);
    float*    shift  = (float*)alloc(6 * CH * 4);
    float*    pooled = (float*)alloc(N_GRAPHS * CH * 4);
    (void)ws_size; (void)n_in; (void)in_sizes; (void)out_size;

    const int n4 = (N_NODES * CH) / 4;
    cast_kernel<<<(n4 + 255) / 256, 256, 0, stream>>>((const float4*)x, (ushort4*)Bh, n4, gcur);
    bin_kernel<<<(N_EDGES + EPB - 1) / EPB, 256, 0, stream>>>(src, dst, gcur, gbuck);
    bscan_kernel<<<1, 256, 0, stream>>>(gcur, gbase);
    place_kernel<<<NB, 256, 0, stream>>>(gcur, gbase, gbuck, rowptr, esrc);
    starts_kernel<<<(N_NODES + 255) / 256, 256, 0, stream>>>(batch, starts, pooled);
    prep_kernel<<<(6 * CH * CH + 6 * CH + 255) / 256, 256, 0, stream>>>(
        W1, W2, Wt, b1, b2, gamma, beta, mean, var, scale, shift);

    const int agg_grid = (N_NODES + 3) / 4;

    for (int i = 0; i < N_LAYERS; ++i) {
        agg_kernel<<<agg_grid, 256, 0, stream>>>((const unsigned*)Bh, rowptr, esrc,
                                                 (unsigned*)Bz);
        mlp_kernel<<<256, 512, 0, stream>>>(Bz,
                                            Wt + (size_t)i * CH * CH,
                                            Wt + (size_t)(3 + i) * CH * CH,
                                            shift + i * CH,
                                            scale + (3 + i) * CH,
                                            shift + (3 + i) * CH,
                                            Bh);
    }

    pool_kernel<<<N_GRAPHS * NSPLIT, 64, 0, stream>>>((const unsigned*)Bh, starts, pooled);
    cls_kernel<<<(N_GRAPHS * OUT_CH + 255) / 256, 256, 0, stream>>>(pooled, Wc, bc, out);
}